// Round 1
// baseline (1312.225 us; speedup 1.0000x reference)
//
#include <hip/hip_runtime.h>

#define NN 64000
#define ET 1024000

// ---------------- graph build ----------------

__global__ void k_deg(const int* __restrict__ ei, int* __restrict__ deg) {
  int e = blockIdx.x * 256 + threadIdx.x;
  if (e < ET) atomicAdd(&deg[ei[e]], 1);
}

__global__ void k_dis(const int* __restrict__ deg, float* __restrict__ dis) {
  int n = blockIdx.x * 256 + threadIdx.x;
  if (n < NN) {
    int d = deg[n];
    dis[n] = d > 0 ? rsqrtf((float)d) : 0.f;
  }
}

__global__ __launch_bounds__(1024) void k_scan(const int* __restrict__ deg,
                                               int* __restrict__ row_ptr,
                                               int* __restrict__ fill_ptr) {
  __shared__ int buf[1024];
  int t = threadIdx.x;
  int running = 0;
  for (int base = 0; base < NN; base += 1024) {
    int idx = base + t;
    int v = (idx < NN) ? deg[idx] : 0;
    buf[t] = v;
    __syncthreads();
    for (int off = 1; off < 1024; off <<= 1) {
      int x = (t >= off) ? buf[t - off] : 0;
      __syncthreads();
      buf[t] += x;
      __syncthreads();
    }
    int excl = buf[t] - v;
    if (idx < NN) { row_ptr[idx] = running + excl; fill_ptr[idx] = running + excl; }
    int tot = buf[1023];
    __syncthreads();
    running += tot;
  }
  if (t == 0) row_ptr[NN] = running;
}

__global__ void k_fill(const int* __restrict__ ei, const float* __restrict__ dis,
                       int* __restrict__ fill_ptr, int2* __restrict__ edata) {
  int e = blockIdx.x * 256 + threadIdx.x;
  if (e >= ET) return;
  int s = ei[e];
  int d = ei[ET + e];
  float nrm = -dis[s] * dis[d];
  int p = atomicAdd(&fill_ptr[d], 1);
  edata[p] = make_int2(s, __float_as_int(nrm));
}

// ---------------- scalar (1-channel) prop for layer 1 ----------------

template<int MODE>
__global__ void k_prop_s(const float* __restrict__ in, const int* __restrict__ row_ptr,
                         const int2* __restrict__ edata, const float* __restrict__ sub,
                         float* __restrict__ out) {
  int n = blockIdx.x * 256 + threadIdx.x;
  if (n >= NN) return;
  int s = row_ptr[n], e = row_ptr[n + 1];
  float acc = 0.f;
  for (int j = s; j < e; ++j) {
    int2 ed = edata[j];
    acc += in[ed.x] * __int_as_float(ed.y);
  }
  out[n] = MODE ? 2.f * acc - sub[n] : acc;
}

__global__ void k_layer1(const float* __restrict__ x, const float* __restrict__ t1,
                         const float* __restrict__ t2, const float* __restrict__ w,
                         const float* __restrict__ b, float* __restrict__ out) {
  int t = threadIdx.x;
  int node = blockIdx.x * 4 + (t >> 6);
  int f = t & 63;
  float v = x[node] * w[f] + t1[node] * w[64 + f] + t2[node] * w[128 + f] + b[f];
  out[(size_t)node * 64 + f] = fmaxf(v, 0.f);
}

// ---------------- 64-channel prop: wave per node, lane = feature ----------------

template<int MODE>
__global__ __launch_bounds__(256) void k_prop64(const float* __restrict__ in,
    const int* __restrict__ row_ptr, const int2* __restrict__ edata,
    const float* __restrict__ sub, float* __restrict__ out) {
  int node = blockIdx.x * 4 + (threadIdx.x >> 6);
  int f = threadIdx.x & 63;
  int s = row_ptr[node], e = row_ptr[node + 1];
  float acc = 0.f;
  int j = s;
  for (; j + 1 < e; j += 2) {
    int2 e0 = edata[j], e1 = edata[j + 1];
    float v0 = in[(size_t)e0.x * 64 + f];
    float v1 = in[(size_t)e1.x * 64 + f];
    acc += v0 * __int_as_float(e0.y);
    acc += v1 * __int_as_float(e1.y);
  }
  if (j < e) {
    int2 e0 = edata[j];
    acc += in[(size_t)e0.x * 64 + f] * __int_as_float(e0.y);
  }
  size_t o = (size_t)node * 64 + f;
  out[o] = MODE ? 2.f * acc - sub[o] : acc;
}

// ---------------- fused cheb matmul: out = T0@W0 + T1@W1 + T2@W2 (+b, relu/res) ----

template<int RELU, int RES>
__global__ __launch_bounds__(256) void k_mat64(
    const float* __restrict__ T0, const float* __restrict__ T1,
    const float* __restrict__ T2, const float* __restrict__ W,  // [3][64][64]
    const float* __restrict__ bias, const float* __restrict__ res,
    float* __restrict__ out) {
  __shared__ float Ws[3 * 64 * 64];
  __shared__ float As[256 * 21];
  int t = threadIdx.x;
  int node0 = blockIdx.x * 256;
  {
    const float4* Wv = (const float4*)W;
    float4* Sv = (float4*)Ws;
    for (int i = t; i < 3072; i += 256) Sv[i] = Wv[i];
  }
  int fi = t & 7;   // output features f = fi + 8*m
  int ni = t >> 3;  // nodes         n = ni + 32*j
  float acc[8][8];
#pragma unroll
  for (int j = 0; j < 8; ++j)
#pragma unroll
    for (int m = 0; m < 8; ++m) acc[j][m] = 0.f;

  for (int p = 0; p < 12; ++p) {
    int k = p >> 2, c0 = (p & 3) << 4;
    const float* Tsel = (k == 0) ? T0 : (k == 1) ? T1 : T2;
    const float* src = Tsel + (size_t)(node0 + t) * 64 + c0;
    float4 v0 = *(const float4*)(src);
    float4 v1 = *(const float4*)(src + 4);
    float4 v2 = *(const float4*)(src + 8);
    float4 v3 = *(const float4*)(src + 12);
    __syncthreads();  // previous phase reads done
    float* dst = &As[t * 21];
    dst[0]=v0.x; dst[1]=v0.y; dst[2]=v0.z; dst[3]=v0.w;
    dst[4]=v1.x; dst[5]=v1.y; dst[6]=v1.z; dst[7]=v1.w;
    dst[8]=v2.x; dst[9]=v2.y; dst[10]=v2.z; dst[11]=v2.w;
    dst[12]=v3.x; dst[13]=v3.y; dst[14]=v3.z; dst[15]=v3.w;
    __syncthreads();
#pragma unroll
    for (int cc = 0; cc < 16; ++cc) {
      int c = c0 + cc;
      float a[8], bb[8];
#pragma unroll
      for (int j = 0; j < 8; ++j) a[j] = As[(ni + 32 * j) * 21 + cc];
      const float* wrow = &Ws[k * 4096 + c * 64];
#pragma unroll
      for (int m = 0; m < 8; ++m) bb[m] = wrow[fi + 8 * m];
#pragma unroll
      for (int j = 0; j < 8; ++j)
#pragma unroll
        for (int m = 0; m < 8; ++m) acc[j][m] += a[j] * bb[m];
    }
  }
#pragma unroll
  for (int j = 0; j < 8; ++j) {
    int node = node0 + ni + 32 * j;
#pragma unroll
    for (int m = 0; m < 8; ++m) {
      int f = fi + 8 * m;
      float v = acc[j][m] + bias[f];
      if (RES) v += res[(size_t)node * 64 + f];
      if (RELU) v = fmaxf(v, 0.f);
      out[(size_t)node * 64 + f] = v;
    }
  }
}

// ---------------- readout ----------------
// lin1: out[g][o] = H.reshape(64,64000) @ W(512,64000)^T ; store transposed r1t[o][g]

__global__ __launch_bounds__(256) void k_lin1(const float* __restrict__ H,
    const float* __restrict__ W, float* __restrict__ r1t) {
  __shared__ float Ah[64 * 65];
  __shared__ float Bw[128 * 65];
  int t = threadIdx.x;
  int ob = (blockIdx.x & 3) * 128;
  int kb = (blockIdx.x >> 2) * 640;
  int gi = t >> 4, oi = t & 15;
  float acc[4][8];
#pragma unroll
  for (int j = 0; j < 4; ++j)
#pragma unroll
    for (int m = 0; m < 8; ++m) acc[j][m] = 0.f;

  for (int ph = 0; ph < 10; ++ph) {
    int j0 = kb + ph * 64;
    __syncthreads();
#pragma unroll
    for (int r = 0; r < 4; ++r) {
      int v = t + 256 * r;
      int g = v >> 4, q = v & 15;
      float4 val = *(const float4*)&H[(size_t)g * 64000 + j0 + q * 4];
      float* dst = &Ah[g * 65 + q * 4];
      dst[0] = val.x; dst[1] = val.y; dst[2] = val.z; dst[3] = val.w;
    }
#pragma unroll
    for (int r = 0; r < 8; ++r) {
      int v = t + 256 * r;
      int o = v >> 4, q = v & 15;
      float4 val = *(const float4*)&W[(size_t)(ob + o) * 64000 + j0 + q * 4];
      float* dst = &Bw[o * 65 + q * 4];
      dst[0] = val.x; dst[1] = val.y; dst[2] = val.z; dst[3] = val.w;
    }
    __syncthreads();
#pragma unroll 8
    for (int kk = 0; kk < 64; ++kk) {
      float a[4], bb[8];
#pragma unroll
      for (int j = 0; j < 4; ++j) a[j] = Ah[(gi + 16 * j) * 65 + kk];
#pragma unroll
      for (int m = 0; m < 8; ++m) bb[m] = Bw[(oi + 16 * m) * 65 + kk];
#pragma unroll
      for (int j = 0; j < 4; ++j)
#pragma unroll
        for (int m = 0; m < 8; ++m) acc[j][m] += a[j] * bb[m];
    }
  }
#pragma unroll
  for (int j = 0; j < 4; ++j) {
    int g = gi + 16 * j;
#pragma unroll
    for (int m = 0; m < 8; ++m) {
      int o = ob + oi + 16 * m;
      atomicAdd(&r1t[(size_t)o * 64 + g], acc[j][m]);
    }
  }
}

__global__ void k_br(float* __restrict__ r1t, const float* __restrict__ b) {
  int i = blockIdx.x * 256 + threadIdx.x;  // over 512*64
  int o = i >> 6;
  r1t[i] = fmaxf(r1t[i] + b[o], 0.f);
}

__global__ void k_lin2(const float* __restrict__ r1t, const float* __restrict__ W,
                       const float* __restrict__ b, float* __restrict__ r2t) {
  int o = blockIdx.x, g = threadIdx.x;
  float acc = 0.f;
#pragma unroll 4
  for (int i = 0; i < 512; ++i) acc += r1t[i * 64 + g] * W[o * 512 + i];
  r2t[o * 64 + g] = fmaxf(acc + b[o], 0.f);
}

__global__ void k_lin3(const float* __restrict__ r2t, const float* __restrict__ W,
                       const float* __restrict__ b, float* __restrict__ out) {
  int o = blockIdx.x, g = threadIdx.x;
  float acc = 0.f;
#pragma unroll 4
  for (int i = 0; i < 512; ++i) acc += r2t[i * 64 + g] * W[o * 512 + i];
  out[g * 10 + o] = fmaxf(acc + b[o], 0.f);
}

// ---------------- launch ----------------

extern "C" void kernel_launch(void* const* d_in, const int* in_sizes, int n_in,
                              void* d_out, int out_size, void* d_ws, size_t ws_size,
                              hipStream_t stream) {
  const float* x    = (const float*)d_in[0];
  const int*   ei   = (const int*)d_in[1];
  const float* w1_1 = (const float*)d_in[3];  const float* b1_1 = (const float*)d_in[4];
  const float* w1_2 = (const float*)d_in[5];  const float* b1_2 = (const float*)d_in[6];
  const float* w1_3 = (const float*)d_in[7];  const float* b1_3 = (const float*)d_in[8];
  const float* w2_1 = (const float*)d_in[9];  const float* b2_1 = (const float*)d_in[10];
  const float* w2_2 = (const float*)d_in[11]; const float* b2_2 = (const float*)d_in[12];
  const float* w3_1 = (const float*)d_in[13]; const float* b3_1 = (const float*)d_in[14];
  const float* l1w  = (const float*)d_in[15]; const float* l1b  = (const float*)d_in[16];
  const float* l2w  = (const float*)d_in[17]; const float* l2b  = (const float*)d_in[18];
  const float* l3w  = (const float*)d_in[19]; const float* l3b  = (const float*)d_in[20];

  char* ws = (char*)d_ws;
  size_t off = 0;
  auto alloc = [&](size_t bytes) -> char* {
    char* p = ws + off;
    off += (bytes + 255) & ~(size_t)255;
    return p;
  };
  float* A    = (float*)alloc((size_t)NN * 64 * 4);
  float* Bb   = (float*)alloc((size_t)NN * 64 * 4);
  float* C    = (float*)alloc((size_t)NN * 64 * 4);
  float* T1   = (float*)alloc((size_t)NN * 64 * 4);
  float* T2   = (float*)alloc((size_t)NN * 64 * 4);
  int*   deg  = (int*)alloc(NN * 4);
  float* dis  = (float*)alloc(NN * 4);
  int*   rowp = (int*)alloc((NN + 1) * 4);
  int*   fillp= (int*)alloc(NN * 4);
  int2*  edata= (int2*)alloc((size_t)ET * 8);
  float* t1s  = (float*)alloc(NN * 4);
  float* t2s  = (float*)alloc(NN * 4);
  float* r1t  = (float*)alloc(512 * 64 * 4);
  float* r2t  = (float*)alloc(512 * 64 * 4);

  hipMemsetAsync(deg, 0, NN * 4, stream);
  hipMemsetAsync(r1t, 0, 512 * 64 * 4, stream);

  k_deg<<<ET / 256, 256, 0, stream>>>(ei, deg);
  k_dis<<<(NN + 255) / 256, 256, 0, stream>>>(deg, dis);
  k_scan<<<1, 1024, 0, stream>>>(deg, rowp, fillp);
  k_fill<<<ET / 256, 256, 0, stream>>>(ei, dis, fillp, edata);

  // layer 1 (1 -> 64 channels)
  k_prop_s<0><<<NN / 256, 256, 0, stream>>>(x, rowp, edata, nullptr, t1s);
  k_prop_s<1><<<NN / 256, 256, 0, stream>>>(t1s, rowp, edata, x, t2s);
  k_layer1<<<NN / 4, 256, 0, stream>>>(x, t1s, t2s, w1_1, b1_1, A);

  auto cheb = [&](const float* in, const float* W, const float* bias,
                  int relu_f, const float* res, float* out) {
    k_prop64<0><<<NN / 4, 256, 0, stream>>>(in, rowp, edata, nullptr, T1);
    k_prop64<1><<<NN / 4, 256, 0, stream>>>(T1, rowp, edata, in, T2);
    if (relu_f)
      k_mat64<1, 0><<<NN / 256, 256, 0, stream>>>(in, T1, T2, W, bias, nullptr, out);
    else
      k_mat64<0, 1><<<NN / 256, 256, 0, stream>>>(in, T1, T2, W, bias, res, out);
  };

  cheb(A,  w1_2, b1_2, 1, nullptr, Bb);  // h = relu(cheb(h))
  cheb(Bb, w1_3, b1_3, 0, A,       C);   // h = cheb(h) + tmp
  cheb(C,  w2_1, b2_1, 1, nullptr, A);
  cheb(A,  w2_2, b2_2, 0, C,       Bb);
  cheb(Bb, w3_1, b3_1, 1, nullptr, C);   // final H in C

  k_lin1<<<400, 256, 0, stream>>>(C, l1w, r1t);
  k_br<<<(512 * 64) / 256, 256, 0, stream>>>(r1t, l1b);
  k_lin2<<<512, 64, 0, stream>>>(r1t, l2w, l2b, r2t);
  k_lin3<<<10, 64, 0, stream>>>(r2t, l3w, l3b, (float*)d_out);
}

// Round 2
// 1103.818 us; speedup vs baseline: 1.1888x; 1.1888x over previous
//
#include <hip/hip_runtime.h>

#define NN 64000
#define ET 1024000

// ---------------- graph build ----------------

__global__ void k_deg(const int* __restrict__ ei, int* __restrict__ deg) {
  int e = blockIdx.x * 256 + threadIdx.x;
  if (e < ET) atomicAdd(&deg[ei[e]], 1);
}

__global__ void k_dis(const int* __restrict__ deg, float* __restrict__ dis) {
  int n = blockIdx.x * 256 + threadIdx.x;
  if (n < NN) {
    int d = deg[n];
    dis[n] = d > 0 ? rsqrtf((float)d) : 0.f;
  }
}

// hierarchical scan: 250 blocks x 256 | 1 block | 250 blocks
__global__ void k_scan1(const int* __restrict__ deg, int* __restrict__ rowp,
                        int* __restrict__ bsum) {
  __shared__ int buf[256];
  int t = threadIdx.x;
  int idx = blockIdx.x * 256 + t;
  int v = deg[idx];
  buf[t] = v;
  __syncthreads();
  for (int off = 1; off < 256; off <<= 1) {
    int x = (t >= off) ? buf[t - off] : 0;
    __syncthreads();
    buf[t] += x;
    __syncthreads();
  }
  rowp[idx] = buf[t] - v;  // exclusive within block
  if (t == 255) bsum[blockIdx.x] = buf[t];
}

__global__ void k_scan2(const int* __restrict__ bsum, int* __restrict__ boff) {
  __shared__ int buf[256];
  int t = threadIdx.x;
  int v = (t < 250) ? bsum[t] : 0;
  buf[t] = v;
  __syncthreads();
  for (int off = 1; off < 256; off <<= 1) {
    int x = (t >= off) ? buf[t - off] : 0;
    __syncthreads();
    buf[t] += x;
    __syncthreads();
  }
  if (t < 250) boff[t] = buf[t] - v;  // exclusive block offsets
}

__global__ void k_scan3(int* __restrict__ rowp, const int* __restrict__ boff,
                        int* __restrict__ fillp) {
  int idx = blockIdx.x * 256 + threadIdx.x;
  int v = rowp[idx] + boff[blockIdx.x];
  rowp[idx] = v;
  fillp[idx] = v;
  if (idx == 0) rowp[NN] = ET;
}

__global__ void k_fill(const int* __restrict__ ei, const float* __restrict__ dis,
                       int* __restrict__ fill_ptr, int2* __restrict__ edata) {
  int e = blockIdx.x * 256 + threadIdx.x;
  if (e >= ET) return;
  int s = ei[e];
  int d = ei[ET + e];
  float nrm = -dis[s] * dis[d];
  int p = atomicAdd(&fill_ptr[d], 1);
  edata[p] = make_int2(s, __float_as_int(nrm));
}

// ---------------- scalar (1-channel) prop for layer 1 ----------------

template<int MODE>
__global__ void k_prop_s(const float* __restrict__ in, const int* __restrict__ row_ptr,
                         const int2* __restrict__ edata, const float* __restrict__ sub,
                         float* __restrict__ out) {
  int n = blockIdx.x * 256 + threadIdx.x;
  if (n >= NN) return;
  int s = row_ptr[n], e = row_ptr[n + 1];
  float acc = 0.f;
  int j = s;
  for (; j + 4 <= e; j += 4) {
    int2 e0 = edata[j], e1 = edata[j + 1], e2 = edata[j + 2], e3 = edata[j + 3];
    float v0 = in[e0.x], v1 = in[e1.x], v2 = in[e2.x], v3 = in[e3.x];
    acc += v0 * __int_as_float(e0.y) + v1 * __int_as_float(e1.y) +
           v2 * __int_as_float(e2.y) + v3 * __int_as_float(e3.y);
  }
  for (; j < e; ++j) {
    int2 ed = edata[j];
    acc += in[ed.x] * __int_as_float(ed.y);
  }
  out[n] = MODE ? 2.f * acc - sub[n] : acc;
}

__global__ void k_layer1(const float* __restrict__ x, const float* __restrict__ t1,
                         const float* __restrict__ t2, const float* __restrict__ w,
                         const float* __restrict__ b, float* __restrict__ out) {
  int t = threadIdx.x;
  int node = blockIdx.x * 4 + (t >> 6);
  int f = t & 63;
  float v = x[node] * w[f] + t1[node] * w[64 + f] + t2[node] * w[128 + f] + b[f];
  out[(size_t)node * 64 + f] = fmaxf(v, 0.f);
}

// ---------------- 64-channel prop: wave per node, lane = feature ----------------
// node index scalarized -> edge records via s_load; 4 gathers in flight per wave.

template<int MODE>
__global__ __launch_bounds__(256) void k_prop64(const float* __restrict__ in,
    const int* __restrict__ row_ptr, const int2* __restrict__ edata,
    const float* __restrict__ sub, float* __restrict__ out) {
  int node = __builtin_amdgcn_readfirstlane(blockIdx.x * 4 + (threadIdx.x >> 6));
  int f = threadIdx.x & 63;
  int s = row_ptr[node], e = row_ptr[node + 1];
  float a0 = 0.f, a1 = 0.f, a2 = 0.f, a3 = 0.f;
  int j = s;
  for (; j + 4 <= e; j += 4) {
    int2 e0 = edata[j], e1 = edata[j + 1], e2 = edata[j + 2], e3 = edata[j + 3];
    float v0 = in[(size_t)e0.x * 64 + f];
    float v1 = in[(size_t)e1.x * 64 + f];
    float v2 = in[(size_t)e2.x * 64 + f];
    float v3 = in[(size_t)e3.x * 64 + f];
    a0 += v0 * __int_as_float(e0.y);
    a1 += v1 * __int_as_float(e1.y);
    a2 += v2 * __int_as_float(e2.y);
    a3 += v3 * __int_as_float(e3.y);
  }
  for (; j < e; ++j) {
    int2 e0 = edata[j];
    a0 += in[(size_t)e0.x * 64 + f] * __int_as_float(e0.y);
  }
  float acc = (a0 + a1) + (a2 + a3);
  size_t o = (size_t)node * 64 + f;
  out[o] = MODE ? 2.f * acc - sub[o] : acc;
}

// ---------------- fused cheb matmul: out = T0@W0 + T1@W1 + T2@W2 (+b, relu/res) ----

template<int RELU, int RES>
__global__ __launch_bounds__(256) void k_mat64(
    const float* __restrict__ T0, const float* __restrict__ T1,
    const float* __restrict__ T2, const float* __restrict__ W,  // [3][64][64]
    const float* __restrict__ bias, const float* __restrict__ res,
    float* __restrict__ out) {
  __shared__ float Ws[3 * 64 * 64];
  __shared__ float As[256 * 21];
  int t = threadIdx.x;
  int node0 = blockIdx.x * 256;
  {
    const float4* Wv = (const float4*)W;
    float4* Sv = (float4*)Ws;
    for (int i = t; i < 3072; i += 256) Sv[i] = Wv[i];
  }
  int fi = t & 7;   // output features f = fi + 8*m
  int ni = t >> 3;  // nodes         n = ni + 32*j
  float acc[8][8];
#pragma unroll
  for (int j = 0; j < 8; ++j)
#pragma unroll
    for (int m = 0; m < 8; ++m) acc[j][m] = 0.f;

  for (int p = 0; p < 12; ++p) {
    int k = p >> 2, c0 = (p & 3) << 4;
    const float* Tsel = (k == 0) ? T0 : (k == 1) ? T1 : T2;
    const float* src = Tsel + (size_t)(node0 + t) * 64 + c0;
    float4 v0 = *(const float4*)(src);
    float4 v1 = *(const float4*)(src + 4);
    float4 v2 = *(const float4*)(src + 8);
    float4 v3 = *(const float4*)(src + 12);
    __syncthreads();  // previous phase reads done
    float* dst = &As[t * 21];
    dst[0]=v0.x; dst[1]=v0.y; dst[2]=v0.z; dst[3]=v0.w;
    dst[4]=v1.x; dst[5]=v1.y; dst[6]=v1.z; dst[7]=v1.w;
    dst[8]=v2.x; dst[9]=v2.y; dst[10]=v2.z; dst[11]=v2.w;
    dst[12]=v3.x; dst[13]=v3.y; dst[14]=v3.z; dst[15]=v3.w;
    __syncthreads();
#pragma unroll
    for (int cc = 0; cc < 16; ++cc) {
      int c = c0 + cc;
      float a[8], bb[8];
#pragma unroll
      for (int j = 0; j < 8; ++j) a[j] = As[(ni + 32 * j) * 21 + cc];
      const float* wrow = &Ws[k * 4096 + c * 64];
#pragma unroll
      for (int m = 0; m < 8; ++m) bb[m] = wrow[fi + 8 * m];
#pragma unroll
      for (int j = 0; j < 8; ++j)
#pragma unroll
        for (int m = 0; m < 8; ++m) acc[j][m] += a[j] * bb[m];
    }
  }
#pragma unroll
  for (int j = 0; j < 8; ++j) {
    int node = node0 + ni + 32 * j;
#pragma unroll
    for (int m = 0; m < 8; ++m) {
      int f = fi + 8 * m;
      float v = acc[j][m] + bias[f];
      if (RES) v += res[(size_t)node * 64 + f];
      if (RELU) v = fmaxf(v, 0.f);
      out[(size_t)node * 64 + f] = v;
    }
  }
}

// ---------------- readout ----------------
// lin1: r1t[o][g] = sum_k H[g][k] * W[o][k].
// Wave-scalar GEMM: lane = g, W rows via wave-uniform scalar loads (zero reuse),
// H chunk staged transposed in LDS. grid = 16 o-blocks x 100 k-blocks.

__global__ __launch_bounds__(256) void k_lin1(const float* __restrict__ H,
    const float* __restrict__ W, float* __restrict__ r1t) {
  __shared__ float Hs[128][65];  // [k][g], padded
  int t = threadIdx.x;
  int ob = (blockIdx.x & 15) * 32;
  int kb = (blockIdx.x >> 4) * 640;
  int lane = t & 63;
  int o0 = __builtin_amdgcn_readfirstlane(ob + (t >> 6) * 8);  // 8 o per wave
  float acc[8];
#pragma unroll
  for (int m = 0; m < 8; ++m) acc[m] = 0.f;

  for (int ph = 0; ph < 5; ++ph) {
    int k0 = kb + ph * 128;
    __syncthreads();
    // stage H[0..63][k0..k0+127] transposed -> Hs[k][g]; coalesced global reads
#pragma unroll
    for (int r = 0; r < 8; ++r) {
      int v = t + 256 * r;          // 0..2047
      int g = v >> 5, q = v & 31;   // 32 float4 per g-row
      float4 val = *(const float4*)&H[(size_t)g * 64000 + k0 + q * 4];
      Hs[q * 4 + 0][g] = val.x;
      Hs[q * 4 + 1][g] = val.y;
      Hs[q * 4 + 2][g] = val.z;
      Hs[q * 4 + 3][g] = val.w;
    }
    __syncthreads();
#pragma unroll 4
    for (int kk = 0; kk < 128; ++kk) {
      float h = Hs[kk][lane];
      const float* wp = W + (size_t)o0 * 64000 + (k0 + kk);
#pragma unroll
      for (int m = 0; m < 8; ++m) acc[m] += wp[(size_t)m * 64000] * h;
    }
  }
#pragma unroll
  for (int m = 0; m < 8; ++m)
    atomicAdd(&r1t[(size_t)(o0 + m) * 64 + lane], acc[m]);
}

__global__ void k_br(float* __restrict__ r1t, const float* __restrict__ b) {
  int i = blockIdx.x * 256 + threadIdx.x;  // over 512*64
  int o = i >> 6;
  r1t[i] = fmaxf(r1t[i] + b[o], 0.f);
}

__global__ void k_lin2(const float* __restrict__ r1t, const float* __restrict__ W,
                       const float* __restrict__ b, float* __restrict__ r2t) {
  int o = blockIdx.x, g = threadIdx.x;
  float acc = 0.f;
#pragma unroll 4
  for (int i = 0; i < 512; ++i) acc += r1t[i * 64 + g] * W[o * 512 + i];
  r2t[o * 64 + g] = fmaxf(acc + b[o], 0.f);
}

__global__ void k_lin3(const float* __restrict__ r2t, const float* __restrict__ W,
                       const float* __restrict__ b, float* __restrict__ out) {
  int o = blockIdx.x, g = threadIdx.x;
  float acc = 0.f;
#pragma unroll 4
  for (int i = 0; i < 512; ++i) acc += r2t[i * 64 + g] * W[o * 512 + i];
  out[g * 10 + o] = fmaxf(acc + b[o], 0.f);
}

// ---------------- launch ----------------

extern "C" void kernel_launch(void* const* d_in, const int* in_sizes, int n_in,
                              void* d_out, int out_size, void* d_ws, size_t ws_size,
                              hipStream_t stream) {
  const float* x    = (const float*)d_in[0];
  const int*   ei   = (const int*)d_in[1];
  const float* w1_1 = (const float*)d_in[3];  const float* b1_1 = (const float*)d_in[4];
  const float* w1_2 = (const float*)d_in[5];  const float* b1_2 = (const float*)d_in[6];
  const float* w1_3 = (const float*)d_in[7];  const float* b1_3 = (const float*)d_in[8];
  const float* w2_1 = (const float*)d_in[9];  const float* b2_1 = (const float*)d_in[10];
  const float* w2_2 = (const float*)d_in[11]; const float* b2_2 = (const float*)d_in[12];
  const float* w3_1 = (const float*)d_in[13]; const float* b3_1 = (const float*)d_in[14];
  const float* l1w  = (const float*)d_in[15]; const float* l1b  = (const float*)d_in[16];
  const float* l2w  = (const float*)d_in[17]; const float* l2b  = (const float*)d_in[18];
  const float* l3w  = (const float*)d_in[19]; const float* l3b  = (const float*)d_in[20];

  char* ws = (char*)d_ws;
  size_t off = 0;
  auto alloc = [&](size_t bytes) -> char* {
    char* p = ws + off;
    off += (bytes + 255) & ~(size_t)255;
    return p;
  };
  float* A    = (float*)alloc((size_t)NN * 64 * 4);
  float* Bb   = (float*)alloc((size_t)NN * 64 * 4);
  float* C    = (float*)alloc((size_t)NN * 64 * 4);
  float* T1   = (float*)alloc((size_t)NN * 64 * 4);
  float* T2   = (float*)alloc((size_t)NN * 64 * 4);
  int*   deg  = (int*)alloc(NN * 4);
  float* dis  = (float*)alloc(NN * 4);
  int*   rowp = (int*)alloc((NN + 1) * 4);
  int*   fillp= (int*)alloc(NN * 4);
  int2*  edata= (int2*)alloc((size_t)ET * 8);
  float* t1s  = (float*)alloc(NN * 4);
  float* t2s  = (float*)alloc(NN * 4);
  float* r1t  = (float*)alloc(512 * 64 * 4);
  float* r2t  = (float*)alloc(512 * 64 * 4);
  int*   bsum = (int*)alloc(256 * 4);
  int*   boff = (int*)alloc(256 * 4);

  hipMemsetAsync(deg, 0, NN * 4, stream);
  hipMemsetAsync(r1t, 0, 512 * 64 * 4, stream);

  k_deg<<<ET / 256, 256, 0, stream>>>(ei, deg);
  k_dis<<<(NN + 255) / 256, 256, 0, stream>>>(deg, dis);
  k_scan1<<<NN / 256, 256, 0, stream>>>(deg, rowp, bsum);
  k_scan2<<<1, 256, 0, stream>>>(bsum, boff);
  k_scan3<<<NN / 256, 256, 0, stream>>>(rowp, boff, fillp);
  k_fill<<<ET / 256, 256, 0, stream>>>(ei, dis, fillp, edata);

  // layer 1 (1 -> 64 channels)
  k_prop_s<0><<<NN / 256, 256, 0, stream>>>(x, rowp, edata, nullptr, t1s);
  k_prop_s<1><<<NN / 256, 256, 0, stream>>>(t1s, rowp, edata, x, t2s);
  k_layer1<<<NN / 4, 256, 0, stream>>>(x, t1s, t2s, w1_1, b1_1, A);

  auto cheb = [&](const float* in, const float* W, const float* bias,
                  int relu_f, const float* res, float* out) {
    k_prop64<0><<<NN / 4, 256, 0, stream>>>(in, rowp, edata, nullptr, T1);
    k_prop64<1><<<NN / 4, 256, 0, stream>>>(T1, rowp, edata, in, T2);
    if (relu_f)
      k_mat64<1, 0><<<NN / 256, 256, 0, stream>>>(in, T1, T2, W, bias, nullptr, out);
    else
      k_mat64<0, 1><<<NN / 256, 256, 0, stream>>>(in, T1, T2, W, bias, res, out);
  };

  cheb(A,  w1_2, b1_2, 1, nullptr, Bb);  // h = relu(cheb(h))
  cheb(Bb, w1_3, b1_3, 0, A,       C);   // h = cheb(h) + tmp
  cheb(C,  w2_1, b2_1, 1, nullptr, A);
  cheb(A,  w2_2, b2_2, 0, C,       Bb);
  cheb(Bb, w3_1, b3_1, 1, nullptr, C);   // final H in C

  k_lin1<<<1600, 256, 0, stream>>>(C, l1w, r1t);
  k_br<<<(512 * 64) / 256, 256, 0, stream>>>(r1t, l1b);
  k_lin2<<<512, 64, 0, stream>>>(r1t, l2w, l2b, r2t);
  k_lin3<<<10, 64, 0, stream>>>(r2t, l3w, l3b, (float*)d_out);
}

// Round 3
// 860.290 us; speedup vs baseline: 1.5253x; 1.2831x over previous
//
#include <hip/hip_runtime.h>

#define NN 64000
#define ET 1024000

// ---------------- graph build ----------------

__global__ void k_deg(const int* __restrict__ ei, int* __restrict__ deg) {
  int e = blockIdx.x * 256 + threadIdx.x;
  if (e < ET) atomicAdd(&deg[ei[e]], 1);
}

__global__ void k_dis(const int* __restrict__ deg, float* __restrict__ dis) {
  int n = blockIdx.x * 256 + threadIdx.x;
  if (n < NN) {
    int d = deg[n];
    dis[n] = d > 0 ? rsqrtf((float)d) : 0.f;
  }
}

// hierarchical scan: 250 blocks x 256 | 1 block | 250 blocks
__global__ void k_scan1(const int* __restrict__ deg, int* __restrict__ rowp,
                        int* __restrict__ bsum) {
  __shared__ int buf[256];
  int t = threadIdx.x;
  int idx = blockIdx.x * 256 + t;
  int v = deg[idx];
  buf[t] = v;
  __syncthreads();
  for (int off = 1; off < 256; off <<= 1) {
    int x = (t >= off) ? buf[t - off] : 0;
    __syncthreads();
    buf[t] += x;
    __syncthreads();
  }
  rowp[idx] = buf[t] - v;  // exclusive within block
  if (t == 255) bsum[blockIdx.x] = buf[t];
}

__global__ void k_scan2(const int* __restrict__ bsum, int* __restrict__ boff) {
  __shared__ int buf[256];
  int t = threadIdx.x;
  int v = (t < 250) ? bsum[t] : 0;
  buf[t] = v;
  __syncthreads();
  for (int off = 1; off < 256; off <<= 1) {
    int x = (t >= off) ? buf[t - off] : 0;
    __syncthreads();
    buf[t] += x;
    __syncthreads();
  }
  if (t < 250) boff[t] = buf[t] - v;  // exclusive block offsets
}

__global__ void k_scan3(int* __restrict__ rowp, const int* __restrict__ boff,
                        int* __restrict__ fillp) {
  int idx = blockIdx.x * 256 + threadIdx.x;
  int v = rowp[idx] + boff[blockIdx.x];
  rowp[idx] = v;
  fillp[idx] = v;
  if (idx == 0) rowp[NN] = ET;
}

__global__ void k_fill(const int* __restrict__ ei, const float* __restrict__ dis,
                       int* __restrict__ fill_ptr, int2* __restrict__ edata) {
  int e = blockIdx.x * 256 + threadIdx.x;
  if (e >= ET) return;
  int s = ei[e];
  int d = ei[ET + e];
  float nrm = -dis[s] * dis[d];
  int p = atomicAdd(&fill_ptr[d], 1);
  edata[p] = make_int2(s, __float_as_int(nrm));
}

// ---------------- scalar (1-channel) prop for layer 1 ----------------

template<int MODE>
__global__ void k_prop_s(const float* __restrict__ in, const int* __restrict__ row_ptr,
                         const int2* __restrict__ edata, const float* __restrict__ sub,
                         float* __restrict__ out) {
  int n = blockIdx.x * 256 + threadIdx.x;
  if (n >= NN) return;
  int s = row_ptr[n], e = row_ptr[n + 1];
  float acc = 0.f;
  int j = s;
  for (; j + 4 <= e; j += 4) {
    int2 e0 = edata[j], e1 = edata[j + 1], e2 = edata[j + 2], e3 = edata[j + 3];
    float v0 = in[e0.x], v1 = in[e1.x], v2 = in[e2.x], v3 = in[e3.x];
    acc += v0 * __int_as_float(e0.y) + v1 * __int_as_float(e1.y) +
           v2 * __int_as_float(e2.y) + v3 * __int_as_float(e3.y);
  }
  for (; j < e; ++j) {
    int2 ed = edata[j];
    acc += in[ed.x] * __int_as_float(ed.y);
  }
  out[n] = MODE ? 2.f * acc - sub[n] : acc;
}

__global__ void k_layer1(const float* __restrict__ x, const float* __restrict__ t1,
                         const float* __restrict__ t2, const float* __restrict__ w,
                         const float* __restrict__ b, float* __restrict__ out) {
  int t = threadIdx.x;
  int node = blockIdx.x * 4 + (t >> 6);
  int f = t & 63;
  float v = x[node] * w[f] + t1[node] * w[64 + f] + t2[node] * w[128 + f] + b[f];
  out[(size_t)node * 64 + f] = fmaxf(v, 0.f);
}

// ---------------- 64-channel prop: wave per node, lane = feature ----------------
// node scalarized -> edge records via s_load; 8 gathers in flight per wave.

template<int MODE>
__global__ __launch_bounds__(256) void k_prop64(const float* __restrict__ in,
    const int* __restrict__ row_ptr, const int2* __restrict__ edata,
    const float* __restrict__ sub, float* __restrict__ out) {
  int node = __builtin_amdgcn_readfirstlane(blockIdx.x * 4 + (threadIdx.x >> 6));
  int f = threadIdx.x & 63;
  int s = row_ptr[node], e = row_ptr[node + 1];
  float a0 = 0.f, a1 = 0.f, a2 = 0.f, a3 = 0.f;
  float a4 = 0.f, a5 = 0.f, a6 = 0.f, a7 = 0.f;
  int j = s;
  for (; j + 8 <= e; j += 8) {
    int2 e0 = edata[j],     e1 = edata[j + 1], e2 = edata[j + 2], e3 = edata[j + 3];
    int2 e4 = edata[j + 4], e5 = edata[j + 5], e6 = edata[j + 6], e7 = edata[j + 7];
    float v0 = in[(size_t)e0.x * 64 + f];
    float v1 = in[(size_t)e1.x * 64 + f];
    float v2 = in[(size_t)e2.x * 64 + f];
    float v3 = in[(size_t)e3.x * 64 + f];
    float v4 = in[(size_t)e4.x * 64 + f];
    float v5 = in[(size_t)e5.x * 64 + f];
    float v6 = in[(size_t)e6.x * 64 + f];
    float v7 = in[(size_t)e7.x * 64 + f];
    a0 += v0 * __int_as_float(e0.y);
    a1 += v1 * __int_as_float(e1.y);
    a2 += v2 * __int_as_float(e2.y);
    a3 += v3 * __int_as_float(e3.y);
    a4 += v4 * __int_as_float(e4.y);
    a5 += v5 * __int_as_float(e5.y);
    a6 += v6 * __int_as_float(e6.y);
    a7 += v7 * __int_as_float(e7.y);
  }
  for (; j + 4 <= e; j += 4) {
    int2 e0 = edata[j], e1 = edata[j + 1], e2 = edata[j + 2], e3 = edata[j + 3];
    float v0 = in[(size_t)e0.x * 64 + f];
    float v1 = in[(size_t)e1.x * 64 + f];
    float v2 = in[(size_t)e2.x * 64 + f];
    float v3 = in[(size_t)e3.x * 64 + f];
    a0 += v0 * __int_as_float(e0.y);
    a1 += v1 * __int_as_float(e1.y);
    a2 += v2 * __int_as_float(e2.y);
    a3 += v3 * __int_as_float(e3.y);
  }
  for (; j < e; ++j) {
    int2 e0 = edata[j];
    a0 += in[(size_t)e0.x * 64 + f] * __int_as_float(e0.y);
  }
  float acc = ((a0 + a1) + (a2 + a3)) + ((a4 + a5) + (a6 + a7));
  size_t o = (size_t)node * 64 + f;
  out[o] = MODE ? 2.f * acc - sub[o] : acc;
}

// ---------------- fused cheb matmul: out = T0@W0 + T1@W1 + T2@W2 (+b, relu/res) ----

template<int RELU, int RES>
__global__ __launch_bounds__(256) void k_mat64(
    const float* __restrict__ T0, const float* __restrict__ T1,
    const float* __restrict__ T2, const float* __restrict__ W,  // [3][64][64]
    const float* __restrict__ bias, const float* __restrict__ res,
    float* __restrict__ out) {
  __shared__ float Ws[3 * 64 * 64];
  __shared__ float As[256 * 21];
  int t = threadIdx.x;
  int node0 = blockIdx.x * 256;
  {
    const float4* Wv = (const float4*)W;
    float4* Sv = (float4*)Ws;
    for (int i = t; i < 3072; i += 256) Sv[i] = Wv[i];
  }
  int fi = t & 7;   // output features f = fi + 8*m
  int ni = t >> 3;  // nodes         n = ni + 32*j
  float acc[8][8];
#pragma unroll
  for (int j = 0; j < 8; ++j)
#pragma unroll
    for (int m = 0; m < 8; ++m) acc[j][m] = 0.f;

  for (int p = 0; p < 12; ++p) {
    int k = p >> 2, c0 = (p & 3) << 4;
    const float* Tsel = (k == 0) ? T0 : (k == 1) ? T1 : T2;
    const float* src = Tsel + (size_t)(node0 + t) * 64 + c0;
    float4 v0 = *(const float4*)(src);
    float4 v1 = *(const float4*)(src + 4);
    float4 v2 = *(const float4*)(src + 8);
    float4 v3 = *(const float4*)(src + 12);
    __syncthreads();  // previous phase reads done
    float* dst = &As[t * 21];
    dst[0]=v0.x; dst[1]=v0.y; dst[2]=v0.z; dst[3]=v0.w;
    dst[4]=v1.x; dst[5]=v1.y; dst[6]=v1.z; dst[7]=v1.w;
    dst[8]=v2.x; dst[9]=v2.y; dst[10]=v2.z; dst[11]=v2.w;
    dst[12]=v3.x; dst[13]=v3.y; dst[14]=v3.z; dst[15]=v3.w;
    __syncthreads();
#pragma unroll
    for (int cc = 0; cc < 16; ++cc) {
      int c = c0 + cc;
      float a[8], bb[8];
#pragma unroll
      for (int j = 0; j < 8; ++j) a[j] = As[(ni + 32 * j) * 21 + cc];
      const float* wrow = &Ws[k * 4096 + c * 64];
#pragma unroll
      for (int m = 0; m < 8; ++m) bb[m] = wrow[fi + 8 * m];
#pragma unroll
      for (int j = 0; j < 8; ++j)
#pragma unroll
        for (int m = 0; m < 8; ++m) acc[j][m] += a[j] * bb[m];
    }
  }
#pragma unroll
  for (int j = 0; j < 8; ++j) {
    int node = node0 + ni + 32 * j;
#pragma unroll
    for (int m = 0; m < 8; ++m) {
      int f = fi + 8 * m;
      float v = acc[j][m] + bias[f];
      if (RES) v += res[(size_t)node * 64 + f];
      if (RELU) v = fmaxf(v, 0.f);
      out[(size_t)node * 64 + f] = v;
    }
  }
}

// ---------------- readout ----------------
// lin1 partials: C[o][g] = sum_k W[o][k] * H[g][k].
// grid = 8 o-blocks x 125 k-splits; 64x64 tile, Ktile=32, LDS-transposed
// operands, 4x4 register tile, deterministic partial buffer (no atomics).

__global__ __launch_bounds__(256) void k_lin1(const float* __restrict__ H,
    const float* __restrict__ W, float* __restrict__ r1p) {
  __shared__ __align__(16) float As[32][68];  // [k][o], pad 68 (272B row = 16B-aligned)
  __shared__ __align__(16) float Bs[32][68];  // [k][g]
  int t = threadIdx.x;
  int bo = blockIdx.x & 7;       // o-block (64 rows)
  int bk = blockIdx.x >> 3;      // k-split (512 k)
  int kb = bk * 512;
  int r = t >> 2, q = t & 3;     // staging: row r (0..63), k-quarter q
  int to = t & 15, tg = t >> 4;  // compute: o = to*4+j, g = tg*4+m
  float acc[4][4];
#pragma unroll
  for (int j = 0; j < 4; ++j)
#pragma unroll
    for (int m = 0; m < 4; ++m) acc[j][m] = 0.f;

  const float* wrow = W + (size_t)(bo * 64 + r) * 64000 + kb + q * 8;
  const float* hrow = H + (size_t)r * 64000 + kb + q * 8;

  for (int tile = 0; tile < 16; ++tile) {
    float4 w0 = *(const float4*)(wrow);
    float4 w1 = *(const float4*)(wrow + 4);
    float4 h0 = *(const float4*)(hrow);
    float4 h1 = *(const float4*)(hrow + 4);
    wrow += 32; hrow += 32;
    __syncthreads();  // previous tile reads done
    {
      float wv[8] = {w0.x, w0.y, w0.z, w0.w, w1.x, w1.y, w1.z, w1.w};
      float hv[8] = {h0.x, h0.y, h0.z, h0.w, h1.x, h1.y, h1.z, h1.w};
#pragma unroll
      for (int i = 0; i < 8; ++i) As[q * 8 + i][r] = wv[i];
#pragma unroll
      for (int i = 0; i < 8; ++i) Bs[q * 8 + i][r] = hv[i];
    }
    __syncthreads();
#pragma unroll 8
    for (int k = 0; k < 32; ++k) {
      float4 a = *(const float4*)&As[k][to * 4];
      float4 b = *(const float4*)&Bs[k][tg * 4];
      float av[4] = {a.x, a.y, a.z, a.w};
      float bv[4] = {b.x, b.y, b.z, b.w};
#pragma unroll
      for (int j = 0; j < 4; ++j)
#pragma unroll
        for (int m = 0; m < 4; ++m) acc[j][m] += av[j] * bv[m];
    }
  }
  // write 64x64 partial tile: r1p[bk][o][g]
  float* dst = r1p + (size_t)bk * 32768 + (size_t)bo * 64 * 64;
#pragma unroll
  for (int j = 0; j < 4; ++j)
#pragma unroll
    for (int m = 0; m < 4; ++m)
      dst[(to * 4 + j) * 64 + tg * 4 + m] = acc[j][m];
}

// reduce 125 partials, add bias, relu -> r1t[o][g]
__global__ void k_red(const float* __restrict__ r1p, const float* __restrict__ b,
                      float* __restrict__ r1t) {
  int i = blockIdx.x * 256 + threadIdx.x;  // 0..32767
  float s = 0.f;
#pragma unroll 5
  for (int p = 0; p < 125; ++p) s += r1p[(size_t)p * 32768 + i];
  int o = i >> 6;
  r1t[i] = fmaxf(s + b[o], 0.f);
}

__global__ void k_lin2(const float* __restrict__ r1t, const float* __restrict__ W,
                       const float* __restrict__ b, float* __restrict__ r2t) {
  int o = blockIdx.x, g = threadIdx.x;
  float acc = 0.f;
#pragma unroll 4
  for (int i = 0; i < 512; ++i) acc += r1t[i * 64 + g] * W[o * 512 + i];
  r2t[o * 64 + g] = fmaxf(acc + b[o], 0.f);
}

__global__ void k_lin3(const float* __restrict__ r2t, const float* __restrict__ W,
                       const float* __restrict__ b, float* __restrict__ out) {
  int o = blockIdx.x, g = threadIdx.x;
  float acc = 0.f;
#pragma unroll 4
  for (int i = 0; i < 512; ++i) acc += r2t[i * 64 + g] * W[o * 512 + i];
  out[g * 10 + o] = fmaxf(acc + b[o], 0.f);
}

// ---------------- launch ----------------

extern "C" void kernel_launch(void* const* d_in, const int* in_sizes, int n_in,
                              void* d_out, int out_size, void* d_ws, size_t ws_size,
                              hipStream_t stream) {
  const float* x    = (const float*)d_in[0];
  const int*   ei   = (const int*)d_in[1];
  const float* w1_1 = (const float*)d_in[3];  const float* b1_1 = (const float*)d_in[4];
  const float* w1_2 = (const float*)d_in[5];  const float* b1_2 = (const float*)d_in[6];
  const float* w1_3 = (const float*)d_in[7];  const float* b1_3 = (const float*)d_in[8];
  const float* w2_1 = (const float*)d_in[9];  const float* b2_1 = (const float*)d_in[10];
  const float* w2_2 = (const float*)d_in[11]; const float* b2_2 = (const float*)d_in[12];
  const float* w3_1 = (const float*)d_in[13]; const float* b3_1 = (const float*)d_in[14];
  const float* l1w  = (const float*)d_in[15]; const float* l1b  = (const float*)d_in[16];
  const float* l2w  = (const float*)d_in[17]; const float* l2b  = (const float*)d_in[18];
  const float* l3w  = (const float*)d_in[19]; const float* l3b  = (const float*)d_in[20];

  char* ws = (char*)d_ws;
  size_t off = 0;
  auto alloc = [&](size_t bytes) -> char* {
    char* p = ws + off;
    off += (bytes + 255) & ~(size_t)255;
    return p;
  };
  float* A    = (float*)alloc((size_t)NN * 64 * 4);
  float* Bb   = (float*)alloc((size_t)NN * 64 * 4);
  float* C    = (float*)alloc((size_t)NN * 64 * 4);
  float* T1   = (float*)alloc((size_t)NN * 64 * 4);
  float* T2   = (float*)alloc((size_t)NN * 64 * 4);
  int*   deg  = (int*)alloc(NN * 4);
  float* dis  = (float*)alloc(NN * 4);
  int*   rowp = (int*)alloc((NN + 1) * 4);
  int*   fillp= (int*)alloc(NN * 4);
  int2*  edata= (int2*)alloc((size_t)ET * 8);
  float* t1s  = (float*)alloc(NN * 4);
  float* t2s  = (float*)alloc(NN * 4);
  float* r1t  = (float*)alloc(512 * 64 * 4);
  float* r2t  = (float*)alloc(512 * 64 * 4);
  int*   bsum = (int*)alloc(256 * 4);
  int*   boff = (int*)alloc(256 * 4);
  float* r1p  = (float*)alloc((size_t)125 * 32768 * 4);

  hipMemsetAsync(deg, 0, NN * 4, stream);

  k_deg<<<ET / 256, 256, 0, stream>>>(ei, deg);
  k_dis<<<(NN + 255) / 256, 256, 0, stream>>>(deg, dis);
  k_scan1<<<NN / 256, 256, 0, stream>>>(deg, rowp, bsum);
  k_scan2<<<1, 256, 0, stream>>>(bsum, boff);
  k_scan3<<<NN / 256, 256, 0, stream>>>(rowp, boff, fillp);
  k_fill<<<ET / 256, 256, 0, stream>>>(ei, dis, fillp, edata);

  // layer 1 (1 -> 64 channels)
  k_prop_s<0><<<NN / 256, 256, 0, stream>>>(x, rowp, edata, nullptr, t1s);
  k_prop_s<1><<<NN / 256, 256, 0, stream>>>(t1s, rowp, edata, x, t2s);
  k_layer1<<<NN / 4, 256, 0, stream>>>(x, t1s, t2s, w1_1, b1_1, A);

  auto cheb = [&](const float* in, const float* W, const float* bias,
                  int relu_f, const float* res, float* out) {
    k_prop64<0><<<NN / 4, 256, 0, stream>>>(in, rowp, edata, nullptr, T1);
    k_prop64<1><<<NN / 4, 256, 0, stream>>>(T1, rowp, edata, in, T2);
    if (relu_f)
      k_mat64<1, 0><<<NN / 256, 256, 0, stream>>>(in, T1, T2, W, bias, nullptr, out);
    else
      k_mat64<0, 1><<<NN / 256, 256, 0, stream>>>(in, T1, T2, W, bias, res, out);
  };

  cheb(A,  w1_2, b1_2, 1, nullptr, Bb);  // h = relu(cheb(h))
  cheb(Bb, w1_3, b1_3, 0, A,       C);   // h = cheb(h) + tmp
  cheb(C,  w2_1, b2_1, 1, nullptr, A);
  cheb(A,  w2_2, b2_2, 0, C,       Bb);
  cheb(Bb, w3_1, b3_1, 1, nullptr, C);   // final H in C

  k_lin1<<<1000, 256, 0, stream>>>(C, l1w, r1p);
  k_red<<<32768 / 256, 256, 0, stream>>>(r1p, l1b, r1t);
  k_lin2<<<512, 64, 0, stream>>>(r1t, l2w, l2b, r2t);
  k_lin3<<<10, 64, 0, stream>>>(r2t, l3w, l3b, (float*)d_out);
}

// Round 4
// 855.026 us; speedup vs baseline: 1.5347x; 1.0062x over previous
//
#include <hip/hip_runtime.h>

#define NN 64000
#define ET 1024000

// ---------------- graph build ----------------

__global__ void k_deg(const int* __restrict__ ei, int* __restrict__ deg) {
  int e = blockIdx.x * 256 + threadIdx.x;
  if (e < ET) atomicAdd(&deg[ei[e]], 1);
}

// hierarchical scan: 250 blocks x 256 | 1 block | 250 blocks  (+ dis folded in)
__global__ void k_scan1(const int* __restrict__ deg, float* __restrict__ dis,
                        int* __restrict__ rowp, int* __restrict__ bsum) {
  __shared__ int buf[256];
  int t = threadIdx.x;
  int idx = blockIdx.x * 256 + t;
  int v = deg[idx];
  dis[idx] = v > 0 ? rsqrtf((float)v) : 0.f;
  buf[t] = v;
  __syncthreads();
  for (int off = 1; off < 256; off <<= 1) {
    int x = (t >= off) ? buf[t - off] : 0;
    __syncthreads();
    buf[t] += x;
    __syncthreads();
  }
  rowp[idx] = buf[t] - v;  // exclusive within block
  if (t == 255) bsum[blockIdx.x] = buf[t];
}

__global__ void k_scan2(const int* __restrict__ bsum, int* __restrict__ boff) {
  __shared__ int buf[256];
  int t = threadIdx.x;
  int v = (t < 250) ? bsum[t] : 0;
  buf[t] = v;
  __syncthreads();
  for (int off = 1; off < 256; off <<= 1) {
    int x = (t >= off) ? buf[t - off] : 0;
    __syncthreads();
    buf[t] += x;
    __syncthreads();
  }
  if (t < 250) boff[t] = buf[t] - v;  // exclusive block offsets
}

__global__ void k_scan3(int* __restrict__ rowp, const int* __restrict__ boff,
                        int* __restrict__ fillp) {
  int idx = blockIdx.x * 256 + threadIdx.x;
  int v = rowp[idx] + boff[blockIdx.x];
  rowp[idx] = v;
  fillp[idx] = v;
  if (idx == 0) rowp[NN] = ET;
}

__global__ void k_fill(const int* __restrict__ ei, const float* __restrict__ dis,
                       int* __restrict__ fill_ptr, int2* __restrict__ edata) {
  int e = blockIdx.x * 256 + threadIdx.x;
  if (e >= ET) return;
  int s = ei[e];
  int d = ei[ET + e];
  float nrm = -dis[s] * dis[d];
  int p = atomicAdd(&fill_ptr[d], 1);
  edata[p] = make_int2(s, __float_as_int(nrm));
}

// ---------------- Chebyshev weight fold ----------------
// out = h*W0 + T1*W1 + (2*L*T1 - h)*W2  ==  h*(W0-W2) + T1*W1 + (L*T1)*(2*W2)
// Transform each [3][n][64] weight set: d0 = s0 - s2, d1 = s1, d2 = 2*s2.

struct WXArgs {
  const float *s0, *s1, *s2, *s3, *s4, *s5;
  float *d0, *d1, *d2, *d3, *d4, *d5;
};

__global__ void k_wx(WXArgs a) {
  int b = blockIdx.x;
  int set = b >> 4;  // 16 blocks per 4096-elem set; block 80 -> set 5 (n=64)
  const float* s;
  float* d;
  int n = (set < 5) ? 4096 : 64;
  switch (set) {
    case 0: s = a.s0; d = a.d0; break;
    case 1: s = a.s1; d = a.d1; break;
    case 2: s = a.s2; d = a.d2; break;
    case 3: s = a.s3; d = a.d3; break;
    case 4: s = a.s4; d = a.d4; break;
    default: s = a.s5; d = a.d5; break;
  }
  int i = (set < 5) ? (b - set * 16) * 256 + threadIdx.x : threadIdx.x;
  if (i < n) {
    d[i]         = s[i] - s[i + 2 * n];
    d[i + n]     = s[i + n];
    d[i + 2 * n] = 2.f * s[i + 2 * n];
  }
}

// ---------------- scalar (1-channel) plain prop for layer 1 ----------------

__global__ void k_prop_s(const float* __restrict__ in, const int* __restrict__ row_ptr,
                         const int2* __restrict__ edata, float* __restrict__ out) {
  int n = blockIdx.x * 256 + threadIdx.x;
  if (n >= NN) return;
  int s = row_ptr[n], e = row_ptr[n + 1];
  float acc = 0.f;
  int j = s;
  for (; j + 4 <= e; j += 4) {
    int2 e0 = edata[j], e1 = edata[j + 1], e2 = edata[j + 2], e3 = edata[j + 3];
    float v0 = in[e0.x], v1 = in[e1.x], v2 = in[e2.x], v3 = in[e3.x];
    acc += v0 * __int_as_float(e0.y) + v1 * __int_as_float(e1.y) +
           v2 * __int_as_float(e2.y) + v3 * __int_as_float(e3.y);
  }
  for (; j < e; ++j) {
    int2 ed = edata[j];
    acc += in[ed.x] * __int_as_float(ed.y);
  }
  out[n] = acc;
}

__global__ void k_layer1(const float* __restrict__ x, const float* __restrict__ t1,
                         const float* __restrict__ g2, const float* __restrict__ w,
                         const float* __restrict__ b, float* __restrict__ out) {
  int t = threadIdx.x;
  int node = blockIdx.x * 4 + (t >> 6);
  int f = t & 63;
  float v = x[node] * w[f] + t1[node] * w[64 + f] + g2[node] * w[128 + f] + b[f];
  out[(size_t)node * 64 + f] = fmaxf(v, 0.f);
}

// ---------------- 64-channel plain prop: wave per node, lane = feature -----
// node scalarized -> edge records via scalar loads; 16 gathers in flight.

__global__ __launch_bounds__(256) void k_prop64(const float* __restrict__ in,
    const int* __restrict__ row_ptr, const int2* __restrict__ edata,
    float* __restrict__ out) {
  int node = __builtin_amdgcn_readfirstlane(blockIdx.x * 4 + (threadIdx.x >> 6));
  int f = threadIdx.x & 63;
  int s = row_ptr[node], e = row_ptr[node + 1];
  float a[16];
#pragma unroll
  for (int i = 0; i < 16; ++i) a[i] = 0.f;
  int j = s;
  for (; j + 16 <= e; j += 16) {
    int2 ed[16];
#pragma unroll
    for (int i = 0; i < 16; ++i) ed[i] = edata[j + i];
    float v[16];
#pragma unroll
    for (int i = 0; i < 16; ++i) v[i] = in[(size_t)ed[i].x * 64 + f];
#pragma unroll
    for (int i = 0; i < 16; ++i) a[i] += v[i] * __int_as_float(ed[i].y);
  }
  for (; j + 8 <= e; j += 8) {
    int2 ed[8];
#pragma unroll
    for (int i = 0; i < 8; ++i) ed[i] = edata[j + i];
    float v[8];
#pragma unroll
    for (int i = 0; i < 8; ++i) v[i] = in[(size_t)ed[i].x * 64 + f];
#pragma unroll
    for (int i = 0; i < 8; ++i) a[i] += v[i] * __int_as_float(ed[i].y);
  }
  for (; j + 4 <= e; j += 4) {
    int2 ed[4];
#pragma unroll
    for (int i = 0; i < 4; ++i) ed[i] = edata[j + i];
    float v[4];
#pragma unroll
    for (int i = 0; i < 4; ++i) v[i] = in[(size_t)ed[i].x * 64 + f];
#pragma unroll
    for (int i = 0; i < 4; ++i) a[i] += v[i] * __int_as_float(ed[i].y);
  }
  for (; j < e; ++j) {
    int2 e0 = edata[j];
    a[0] += in[(size_t)e0.x * 64 + f] * __int_as_float(e0.y);
  }
#pragma unroll
  for (int i = 0; i < 8; ++i) a[i] += a[i + 8];
#pragma unroll
  for (int i = 0; i < 4; ++i) a[i] += a[i + 4];
  float acc = (a[0] + a[1]) + (a[2] + a[3]);
  out[(size_t)node * 64 + f] = acc;
}

// ---------------- fused cheb matmul: out = T0@W0' + T1@W1' + G2@W2' (+b, relu/res)

template<int RELU, int RES>
__global__ __launch_bounds__(256) void k_mat64(
    const float* __restrict__ T0, const float* __restrict__ T1,
    const float* __restrict__ T2, const float* __restrict__ W,  // [3][64][64] folded
    const float* __restrict__ bias, const float* __restrict__ res,
    float* __restrict__ out) {
  __shared__ float Ws[3 * 64 * 64];
  __shared__ float As[256 * 21];
  int t = threadIdx.x;
  int node0 = blockIdx.x * 256;
  {
    const float4* Wv = (const float4*)W;
    float4* Sv = (float4*)Ws;
    for (int i = t; i < 3072; i += 256) Sv[i] = Wv[i];
  }
  int fi = t & 7;   // output features f = fi + 8*m
  int ni = t >> 3;  // nodes         n = ni + 32*j
  float acc[8][8];
#pragma unroll
  for (int j = 0; j < 8; ++j)
#pragma unroll
    for (int m = 0; m < 8; ++m) acc[j][m] = 0.f;

  for (int p = 0; p < 12; ++p) {
    int k = p >> 2, c0 = (p & 3) << 4;
    const float* Tsel = (k == 0) ? T0 : (k == 1) ? T1 : T2;
    const float* src = Tsel + (size_t)(node0 + t) * 64 + c0;
    float4 v0 = *(const float4*)(src);
    float4 v1 = *(const float4*)(src + 4);
    float4 v2 = *(const float4*)(src + 8);
    float4 v3 = *(const float4*)(src + 12);
    __syncthreads();  // previous phase reads done
    float* dst = &As[t * 21];
    dst[0]=v0.x; dst[1]=v0.y; dst[2]=v0.z; dst[3]=v0.w;
    dst[4]=v1.x; dst[5]=v1.y; dst[6]=v1.z; dst[7]=v1.w;
    dst[8]=v2.x; dst[9]=v2.y; dst[10]=v2.z; dst[11]=v2.w;
    dst[12]=v3.x; dst[13]=v3.y; dst[14]=v3.z; dst[15]=v3.w;
    __syncthreads();
#pragma unroll
    for (int cc = 0; cc < 16; ++cc) {
      int c = c0 + cc;
      float a[8], bb[8];
#pragma unroll
      for (int j = 0; j < 8; ++j) a[j] = As[(ni + 32 * j) * 21 + cc];
      const float* wrow = &Ws[k * 4096 + c * 64];
#pragma unroll
      for (int m = 0; m < 8; ++m) bb[m] = wrow[fi + 8 * m];
#pragma unroll
      for (int j = 0; j < 8; ++j)
#pragma unroll
        for (int m = 0; m < 8; ++m) acc[j][m] += a[j] * bb[m];
    }
  }
#pragma unroll
  for (int j = 0; j < 8; ++j) {
    int node = node0 + ni + 32 * j;
#pragma unroll
    for (int m = 0; m < 8; ++m) {
      int f = fi + 8 * m;
      float v = acc[j][m] + bias[f];
      if (RES) v += res[(size_t)node * 64 + f];
      if (RELU) v = fmaxf(v, 0.f);
      out[(size_t)node * 64 + f] = v;
    }
  }
}

// ---------------- readout ----------------
// lin1 partials: C[o][g] = sum_k W[o][k] * H[g][k].
// grid = 8 o-blocks x 125 k-splits; 64x64 tile, Ktile=32, LDS-transposed
// operands, 4x4 register tile, deterministic partial buffer (no atomics).

__global__ __launch_bounds__(256) void k_lin1(const float* __restrict__ H,
    const float* __restrict__ W, float* __restrict__ r1p) {
  __shared__ __align__(16) float As[32][68];  // [k][o], pad 68 (272B row = 16B-aligned)
  __shared__ __align__(16) float Bs[32][68];  // [k][g]
  int t = threadIdx.x;
  int bo = blockIdx.x & 7;       // o-block (64 rows)
  int bk = blockIdx.x >> 3;      // k-split (512 k)
  int kb = bk * 512;
  int r = t >> 2, q = t & 3;     // staging: row r (0..63), k-quarter q
  int to = t & 15, tg = t >> 4;  // compute: o = to*4+j, g = tg*4+m
  float acc[4][4];
#pragma unroll
  for (int j = 0; j < 4; ++j)
#pragma unroll
    for (int m = 0; m < 4; ++m) acc[j][m] = 0.f;

  const float* wrow = W + (size_t)(bo * 64 + r) * 64000 + kb + q * 8;
  const float* hrow = H + (size_t)r * 64000 + kb + q * 8;

  for (int tile = 0; tile < 16; ++tile) {
    float4 w0 = *(const float4*)(wrow);
    float4 w1 = *(const float4*)(wrow + 4);
    float4 h0 = *(const float4*)(hrow);
    float4 h1 = *(const float4*)(hrow + 4);
    wrow += 32; hrow += 32;
    __syncthreads();  // previous tile reads done
    {
      float wv[8] = {w0.x, w0.y, w0.z, w0.w, w1.x, w1.y, w1.z, w1.w};
      float hv[8] = {h0.x, h0.y, h0.z, h0.w, h1.x, h1.y, h1.z, h1.w};
#pragma unroll
      for (int i = 0; i < 8; ++i) As[q * 8 + i][r] = wv[i];
#pragma unroll
      for (int i = 0; i < 8; ++i) Bs[q * 8 + i][r] = hv[i];
    }
    __syncthreads();
#pragma unroll 8
    for (int k = 0; k < 32; ++k) {
      float4 a = *(const float4*)&As[k][to * 4];
      float4 b = *(const float4*)&Bs[k][tg * 4];
      float av[4] = {a.x, a.y, a.z, a.w};
      float bv[4] = {b.x, b.y, b.z, b.w};
#pragma unroll
      for (int j = 0; j < 4; ++j)
#pragma unroll
        for (int m = 0; m < 4; ++m) acc[j][m] += av[j] * bv[m];
    }
  }
  // write 64x64 partial tile: r1p[bk][o][g]
  float* dst = r1p + (size_t)bk * 32768 + (size_t)bo * 64 * 64;
#pragma unroll
  for (int j = 0; j < 4; ++j)
#pragma unroll
    for (int m = 0; m < 4; ++m)
      dst[(to * 4 + j) * 64 + tg * 4 + m] = acc[j][m];
}

// reduce 125 partials, add bias, relu -> r1t[o][g]
__global__ void k_red(const float* __restrict__ r1p, const float* __restrict__ b,
                      float* __restrict__ r1t) {
  int i = blockIdx.x * 256 + threadIdx.x;  // 0..32767
  float s = 0.f;
#pragma unroll 5
  for (int p = 0; p < 125; ++p) s += r1p[(size_t)p * 32768 + i];
  int o = i >> 6;
  r1t[i] = fmaxf(s + b[o], 0.f);
}

__global__ void k_lin2(const float* __restrict__ r1t, const float* __restrict__ W,
                       const float* __restrict__ b, float* __restrict__ r2t) {
  int o = blockIdx.x, g = threadIdx.x;
  float acc = 0.f;
#pragma unroll 4
  for (int i = 0; i < 512; ++i) acc += r1t[i * 64 + g] * W[o * 512 + i];
  r2t[o * 64 + g] = fmaxf(acc + b[o], 0.f);
}

__global__ void k_lin3(const float* __restrict__ r2t, const float* __restrict__ W,
                       const float* __restrict__ b, float* __restrict__ out) {
  int o = blockIdx.x, g = threadIdx.x;
  float acc = 0.f;
#pragma unroll 4
  for (int i = 0; i < 512; ++i) acc += r2t[i * 64 + g] * W[o * 512 + i];
  out[g * 10 + o] = fmaxf(acc + b[o], 0.f);
}

// ---------------- launch ----------------

extern "C" void kernel_launch(void* const* d_in, const int* in_sizes, int n_in,
                              void* d_out, int out_size, void* d_ws, size_t ws_size,
                              hipStream_t stream) {
  const float* x    = (const float*)d_in[0];
  const int*   ei   = (const int*)d_in[1];
  const float* w1_1 = (const float*)d_in[3];  const float* b1_1 = (const float*)d_in[4];
  const float* w1_2 = (const float*)d_in[5];  const float* b1_2 = (const float*)d_in[6];
  const float* w1_3 = (const float*)d_in[7];  const float* b1_3 = (const float*)d_in[8];
  const float* w2_1 = (const float*)d_in[9];  const float* b2_1 = (const float*)d_in[10];
  const float* w2_2 = (const float*)d_in[11]; const float* b2_2 = (const float*)d_in[12];
  const float* w3_1 = (const float*)d_in[13]; const float* b3_1 = (const float*)d_in[14];
  const float* l1w  = (const float*)d_in[15]; const float* l1b  = (const float*)d_in[16];
  const float* l2w  = (const float*)d_in[17]; const float* l2b  = (const float*)d_in[18];
  const float* l3w  = (const float*)d_in[19]; const float* l3b  = (const float*)d_in[20];

  char* ws = (char*)d_ws;
  size_t off = 0;
  auto alloc = [&](size_t bytes) -> char* {
    char* p = ws + off;
    off += (bytes + 255) & ~(size_t)255;
    return p;
  };
  float* A    = (float*)alloc((size_t)NN * 64 * 4);
  float* Bb   = (float*)alloc((size_t)NN * 64 * 4);
  float* C    = (float*)alloc((size_t)NN * 64 * 4);
  float* T1   = (float*)alloc((size_t)NN * 64 * 4);
  float* T2   = (float*)alloc((size_t)NN * 64 * 4);
  int*   deg  = (int*)alloc(NN * 4);
  float* dis  = (float*)alloc(NN * 4);
  int*   rowp = (int*)alloc((NN + 1) * 4);
  int*   fillp= (int*)alloc(NN * 4);
  int2*  edata= (int2*)alloc((size_t)ET * 8);
  float* t1s  = (float*)alloc(NN * 4);
  float* g2s  = (float*)alloc(NN * 4);
  float* r1t  = (float*)alloc(512 * 64 * 4);
  float* r2t  = (float*)alloc(512 * 64 * 4);
  int*   bsum = (int*)alloc(256 * 4);
  int*   boff = (int*)alloc(256 * 4);
  float* r1p  = (float*)alloc((size_t)125 * 32768 * 4);
  float* wt11 = (float*)alloc(192 * 4);
  float* wt12 = (float*)alloc(12288 * 4);
  float* wt13 = (float*)alloc(12288 * 4);
  float* wt21 = (float*)alloc(12288 * 4);
  float* wt22 = (float*)alloc(12288 * 4);
  float* wt31 = (float*)alloc(12288 * 4);

  hipMemsetAsync(deg, 0, NN * 4, stream);

  k_deg<<<ET / 256, 256, 0, stream>>>(ei, deg);
  k_scan1<<<NN / 256, 256, 0, stream>>>(deg, dis, rowp, bsum);
  k_scan2<<<1, 256, 0, stream>>>(bsum, boff);
  k_scan3<<<NN / 256, 256, 0, stream>>>(rowp, boff, fillp);
  k_fill<<<ET / 256, 256, 0, stream>>>(ei, dis, fillp, edata);

  WXArgs wx{w1_2, w1_3, w2_1, w2_2, w3_1, w1_1,
            wt12, wt13, wt21, wt22, wt31, wt11};
  k_wx<<<81, 256, 0, stream>>>(wx);

  // layer 1 (1 -> 64 channels)
  k_prop_s<<<NN / 256, 256, 0, stream>>>(x, rowp, edata, t1s);
  k_prop_s<<<NN / 256, 256, 0, stream>>>(t1s, rowp, edata, g2s);
  k_layer1<<<NN / 4, 256, 0, stream>>>(x, t1s, g2s, wt11, b1_1, A);

  auto cheb = [&](const float* in, const float* Wt, const float* bias,
                  int relu_f, const float* res, float* out) {
    k_prop64<<<NN / 4, 256, 0, stream>>>(in, rowp, edata, T1);
    k_prop64<<<NN / 4, 256, 0, stream>>>(T1, rowp, edata, T2);
    if (relu_f)
      k_mat64<1, 0><<<NN / 256, 256, 0, stream>>>(in, T1, T2, Wt, bias, nullptr, out);
    else
      k_mat64<0, 1><<<NN / 256, 256, 0, stream>>>(in, T1, T2, Wt, bias, res, out);
  };

  cheb(A,  wt12, b1_2, 1, nullptr, Bb);  // h = relu(cheb(h))
  cheb(Bb, wt13, b1_3, 0, A,       C);   // h = cheb(h) + tmp
  cheb(C,  wt21, b2_1, 1, nullptr, A);
  cheb(A,  wt22, b2_2, 0, C,       Bb);
  cheb(Bb, wt31, b3_1, 1, nullptr, C);   // final H in C

  k_lin1<<<1000, 256, 0, stream>>>(C, l1w, r1p);
  k_red<<<32768 / 256, 256, 0, stream>>>(r1p, l1b, r1t);
  k_lin2<<<512, 64, 0, stream>>>(r1t, l2w, l2b, r2t);
  k_lin3<<<10, 64, 0, stream>>>(r2t, l3w, l3b, (float*)d_out);
}

// Round 5
// 733.513 us; speedup vs baseline: 1.7890x; 1.1657x over previous
//
#include <hip/hip_runtime.h>
#include <hip/hip_fp16.h>

#define NN 64000
#define ET 1024000

typedef __attribute__((ext_vector_type(8))) short short8;

__device__ inline float h2f(__half h) { return __half2float(h); }
__device__ inline void dec_edge(unsigned p, int& src, float& w) {
  src = (int)(p & 0xFFFFu);
  w = __half2float(__ushort_as_half((unsigned short)(p >> 16)));
}

// ---------------- graph build ----------------

__global__ void k_deg(const int* __restrict__ ei, int* __restrict__ deg) {
  int e = blockIdx.x * 256 + threadIdx.x;
  if (e < ET) atomicAdd(&deg[ei[e]], 1);
}

// hierarchical scan: 250 blocks x 256 | 1 block | 250 blocks  (+ dis folded in)
__global__ void k_scan1(const int* __restrict__ deg, float* __restrict__ dis,
                        int* __restrict__ rowp, int* __restrict__ bsum) {
  __shared__ int buf[256];
  int t = threadIdx.x;
  int idx = blockIdx.x * 256 + t;
  int v = deg[idx];
  dis[idx] = v > 0 ? rsqrtf((float)v) : 0.f;
  buf[t] = v;
  __syncthreads();
  for (int off = 1; off < 256; off <<= 1) {
    int x = (t >= off) ? buf[t - off] : 0;
    __syncthreads();
    buf[t] += x;
    __syncthreads();
  }
  rowp[idx] = buf[t] - v;  // exclusive within block
  if (t == 255) bsum[blockIdx.x] = buf[t];
}

__global__ void k_scan2(const int* __restrict__ bsum, int* __restrict__ boff) {
  __shared__ int buf[256];
  int t = threadIdx.x;
  int v = (t < 250) ? bsum[t] : 0;
  buf[t] = v;
  __syncthreads();
  for (int off = 1; off < 256; off <<= 1) {
    int x = (t >= off) ? buf[t - off] : 0;
    __syncthreads();
    buf[t] += x;
    __syncthreads();
  }
  if (t < 250) boff[t] = buf[t] - v;  // exclusive block offsets
}

__global__ void k_scan3(int* __restrict__ rowp, const int* __restrict__ boff,
                        int* __restrict__ fillp) {
  int idx = blockIdx.x * 256 + threadIdx.x;
  int v = rowp[idx] + boff[blockIdx.x];
  rowp[idx] = v;
  fillp[idx] = v;
  if (idx == 0) rowp[NN] = ET;
}

// packed edge record: low16 = src node, high16 = f16 norm
__global__ void k_fill(const int* __restrict__ ei, const float* __restrict__ dis,
                       int* __restrict__ fill_ptr, unsigned* __restrict__ edata) {
  int e = blockIdx.x * 256 + threadIdx.x;
  if (e >= ET) return;
  int s = ei[e];
  int d = ei[ET + e];
  float nrm = -dis[s] * dis[d];
  unsigned packed = (unsigned)s |
      ((unsigned)__half_as_ushort(__float2half(nrm)) << 16);
  int p = atomicAdd(&fill_ptr[d], 1);
  edata[p] = packed;
}

// ---------------- Chebyshev weight fold ----------------
// out = h*W0 + T1*W1 + (2*L*T1 - h)*W2  ==  h*(W0-W2) + T1*W1 + (L*T1)*(2*W2)

struct WXArgs {
  const float *s0, *s1, *s2, *s3, *s4, *s5;
  float *d0, *d1, *d2, *d3, *d4, *d5;
};

__global__ void k_wx(WXArgs a) {
  int b = blockIdx.x;
  int set = b >> 4;  // 16 blocks per 4096-elem set; block 80 -> set 5 (n=64)
  const float* s;
  float* d;
  int n = (set < 5) ? 4096 : 64;
  switch (set) {
    case 0: s = a.s0; d = a.d0; break;
    case 1: s = a.s1; d = a.d1; break;
    case 2: s = a.s2; d = a.d2; break;
    case 3: s = a.s3; d = a.d3; break;
    case 4: s = a.s4; d = a.d4; break;
    default: s = a.s5; d = a.d5; break;
  }
  int i = (set < 5) ? (b - set * 16) * 256 + threadIdx.x : threadIdx.x;
  if (i < n) {
    d[i]         = s[i] - s[i + 2 * n];
    d[i + n]     = s[i + n];
    d[i + 2 * n] = 2.f * s[i + 2 * n];
  }
}

// ---------------- scalar (1-channel) plain prop for layer 1 (f32) ----------

__global__ void k_prop_s(const float* __restrict__ in, const int* __restrict__ row_ptr,
                         const unsigned* __restrict__ edata, float* __restrict__ out) {
  int n = blockIdx.x * 256 + threadIdx.x;
  if (n >= NN) return;
  int s = row_ptr[n], e = row_ptr[n + 1];
  float acc = 0.f;
  int j = s;
  for (; j + 4 <= e; j += 4) {
    int s0, s1, s2, s3; float w0, w1, w2, w3;
    dec_edge(edata[j], s0, w0); dec_edge(edata[j + 1], s1, w1);
    dec_edge(edata[j + 2], s2, w2); dec_edge(edata[j + 3], s3, w3);
    acc += in[s0] * w0 + in[s1] * w1 + in[s2] * w2 + in[s3] * w3;
  }
  for (; j < e; ++j) {
    int s0; float w0;
    dec_edge(edata[j], s0, w0);
    acc += in[s0] * w0;
  }
  out[n] = acc;
}

__global__ void k_layer1(const float* __restrict__ x, const float* __restrict__ t1,
                         const float* __restrict__ g2, const float* __restrict__ w,
                         const float* __restrict__ b, __half* __restrict__ out) {
  int t = threadIdx.x;
  int node = blockIdx.x * 4 + (t >> 6);
  int f = t & 63;
  float v = x[node] * w[f] + t1[node] * w[64 + f] + g2[node] * w[128 + f] + b[f];
  out[(size_t)node * 64 + f] = __float2half(fmaxf(v, 0.f));
}

// ---------------- 64-channel plain prop (f16 features): wave/node, lane=feat

__global__ __launch_bounds__(256) void k_prop64(const __half* __restrict__ in,
    const int* __restrict__ row_ptr, const unsigned* __restrict__ edata,
    __half* __restrict__ out) {
  int node = __builtin_amdgcn_readfirstlane(blockIdx.x * 4 + (threadIdx.x >> 6));
  int f = threadIdx.x & 63;
  int s = row_ptr[node], e = row_ptr[node + 1];
  float a[16];
#pragma unroll
  for (int i = 0; i < 16; ++i) a[i] = 0.f;
  int j = s;
  for (; j + 16 <= e; j += 16) {
    int si[16]; float wi[16];
#pragma unroll
    for (int i = 0; i < 16; ++i) dec_edge(edata[j + i], si[i], wi[i]);
    float v[16];
#pragma unroll
    for (int i = 0; i < 16; ++i) v[i] = h2f(in[(size_t)si[i] * 64 + f]);
#pragma unroll
    for (int i = 0; i < 16; ++i) a[i] += v[i] * wi[i];
  }
  for (; j + 8 <= e; j += 8) {
    int si[8]; float wi[8];
#pragma unroll
    for (int i = 0; i < 8; ++i) dec_edge(edata[j + i], si[i], wi[i]);
    float v[8];
#pragma unroll
    for (int i = 0; i < 8; ++i) v[i] = h2f(in[(size_t)si[i] * 64 + f]);
#pragma unroll
    for (int i = 0; i < 8; ++i) a[i] += v[i] * wi[i];
  }
  for (; j + 4 <= e; j += 4) {
    int si[4]; float wi[4];
#pragma unroll
    for (int i = 0; i < 4; ++i) dec_edge(edata[j + i], si[i], wi[i]);
    float v[4];
#pragma unroll
    for (int i = 0; i < 4; ++i) v[i] = h2f(in[(size_t)si[i] * 64 + f]);
#pragma unroll
    for (int i = 0; i < 4; ++i) a[i] += v[i] * wi[i];
  }
  for (; j < e; ++j) {
    int s0; float w0;
    dec_edge(edata[j], s0, w0);
    a[0] += h2f(in[(size_t)s0 * 64 + f]) * w0;
  }
#pragma unroll
  for (int i = 0; i < 8; ++i) a[i] += a[i + 8];
#pragma unroll
  for (int i = 0; i < 4; ++i) a[i] += a[i + 4];
  float acc = (a[0] + a[1]) + (a[2] + a[3]);
  out[(size_t)node * 64 + f] = __float2half(acc);
}

// ------- fused cheb matmul: out = T0@W0' + T1@W1' + G2@W2' (+b, relu/res), f16 IO

template<int RELU, int RES>
__global__ __launch_bounds__(256) void k_mat64(
    const __half* __restrict__ T0, const __half* __restrict__ T1,
    const __half* __restrict__ T2, const float* __restrict__ W,  // [3][64][64] folded
    const float* __restrict__ bias, const __half* __restrict__ res,
    __half* __restrict__ out) {
  __shared__ float Ws[3 * 64 * 64];
  __shared__ float As[256 * 21];
  int t = threadIdx.x;
  int node0 = blockIdx.x * 256;
  {
    const float4* Wv = (const float4*)W;
    float4* Sv = (float4*)Ws;
    for (int i = t; i < 3072; i += 256) Sv[i] = Wv[i];
  }
  int fi = t & 7;   // output features f = fi + 8*m
  int ni = t >> 3;  // nodes         n = ni + 32*j
  float acc[8][8];
#pragma unroll
  for (int j = 0; j < 8; ++j)
#pragma unroll
    for (int m = 0; m < 8; ++m) acc[j][m] = 0.f;

  for (int p = 0; p < 12; ++p) {
    int k = p >> 2, c0 = (p & 3) << 4;
    const __half* Tsel = (k == 0) ? T0 : (k == 1) ? T1 : T2;
    const __half* src = Tsel + (size_t)(node0 + t) * 64 + c0;
    short8 r0 = *(const short8*)(src);
    short8 r1 = *(const short8*)(src + 8);
    __syncthreads();  // previous phase reads done
    float* dst = &As[t * 21];
#pragma unroll
    for (int i = 0; i < 8; ++i) dst[i] = h2f(__ushort_as_half((unsigned short)r0[i]));
#pragma unroll
    for (int i = 0; i < 8; ++i) dst[8 + i] = h2f(__ushort_as_half((unsigned short)r1[i]));
    __syncthreads();
#pragma unroll
    for (int cc = 0; cc < 16; ++cc) {
      int c = c0 + cc;
      float a[8], bb[8];
#pragma unroll
      for (int j = 0; j < 8; ++j) a[j] = As[(ni + 32 * j) * 21 + cc];
      const float* wrow = &Ws[k * 4096 + c * 64];
#pragma unroll
      for (int m = 0; m < 8; ++m) bb[m] = wrow[fi + 8 * m];
#pragma unroll
      for (int j = 0; j < 8; ++j)
#pragma unroll
        for (int m = 0; m < 8; ++m) acc[j][m] += a[j] * bb[m];
    }
  }
#pragma unroll
  for (int j = 0; j < 8; ++j) {
    int node = node0 + ni + 32 * j;
#pragma unroll
    for (int m = 0; m < 8; ++m) {
      int f = fi + 8 * m;
      float v = acc[j][m] + bias[f];
      if (RES) v += h2f(res[(size_t)node * 64 + f]);
      if (RELU) v = fmaxf(v, 0.f);
      out[(size_t)node * 64 + f] = __float2half(v);
    }
  }
}

// ---------------- readout ----------------
// lin1 partials: C[o][g] = sum_k W[o][k] * H[g][k].  H is f16, W f32.
// grid = 8 o-blocks x 125 k-splits; 64x64 tile, Ktile=32, LDS-transposed
// operands, 4x4 register tile, deterministic partial buffer (no atomics).

__global__ __launch_bounds__(256) void k_lin1(const __half* __restrict__ H,
    const float* __restrict__ W, float* __restrict__ r1p) {
  __shared__ __align__(16) float As[32][68];  // [k][o], pad 68
  __shared__ __align__(16) float Bs[32][68];  // [k][g]
  int t = threadIdx.x;
  int bo = blockIdx.x & 7;       // o-block (64 rows)
  int bk = blockIdx.x >> 3;      // k-split (512 k)
  int kb = bk * 512;
  int r = t >> 2, q = t & 3;     // staging: row r (0..63), k-quarter q
  int to = t & 15, tg = t >> 4;  // compute: o = to*4+j, g = tg*4+m
  float acc[4][4];
#pragma unroll
  for (int j = 0; j < 4; ++j)
#pragma unroll
    for (int m = 0; m < 4; ++m) acc[j][m] = 0.f;

  const float* wrow = W + (size_t)(bo * 64 + r) * 64000 + kb + q * 8;
  const __half* hrow = H + (size_t)r * 64000 + kb + q * 8;

  for (int tile = 0; tile < 16; ++tile) {
    float4 w0 = *(const float4*)(wrow);
    float4 w1 = *(const float4*)(wrow + 4);
    short8 hr = *(const short8*)(hrow);
    wrow += 32; hrow += 32;
    __syncthreads();  // previous tile reads done
    {
      float wv[8] = {w0.x, w0.y, w0.z, w0.w, w1.x, w1.y, w1.z, w1.w};
#pragma unroll
      for (int i = 0; i < 8; ++i) As[q * 8 + i][r] = wv[i];
#pragma unroll
      for (int i = 0; i < 8; ++i)
        Bs[q * 8 + i][r] = h2f(__ushort_as_half((unsigned short)hr[i]));
    }
    __syncthreads();
#pragma unroll 8
    for (int k = 0; k < 32; ++k) {
      float4 a = *(const float4*)&As[k][to * 4];
      float4 b = *(const float4*)&Bs[k][tg * 4];
      float av[4] = {a.x, a.y, a.z, a.w};
      float bv[4] = {b.x, b.y, b.z, b.w};
#pragma unroll
      for (int j = 0; j < 4; ++j)
#pragma unroll
        for (int m = 0; m < 4; ++m) acc[j][m] += av[j] * bv[m];
    }
  }
  // write 64x64 partial tile: r1p[bk][o][g]
  float* dst = r1p + (size_t)bk * 32768 + (size_t)bo * 64 * 64;
#pragma unroll
  for (int j = 0; j < 4; ++j)
#pragma unroll
    for (int m = 0; m < 4; ++m)
      dst[(to * 4 + j) * 64 + tg * 4 + m] = acc[j][m];
}

// reduce 125 partials, add bias, relu -> r1t[o][g]
__global__ void k_red(const float* __restrict__ r1p, const float* __restrict__ b,
                      float* __restrict__ r1t) {
  int i = blockIdx.x * 256 + threadIdx.x;  // 0..32767
  float s = 0.f;
#pragma unroll 5
  for (int p = 0; p < 125; ++p) s += r1p[(size_t)p * 32768 + i];
  int o = i >> 6;
  r1t[i] = fmaxf(s + b[o], 0.f);
}

__global__ void k_lin2(const float* __restrict__ r1t, const float* __restrict__ W,
                       const float* __restrict__ b, float* __restrict__ r2t) {
  int o = blockIdx.x, g = threadIdx.x;
  float acc = 0.f;
#pragma unroll 4
  for (int i = 0; i < 512; ++i) acc += r1t[i * 64 + g] * W[o * 512 + i];
  r2t[o * 64 + g] = fmaxf(acc + b[o], 0.f);
}

__global__ void k_lin3(const float* __restrict__ r2t, const float* __restrict__ W,
                       const float* __restrict__ b, float* __restrict__ out) {
  int o = blockIdx.x, g = threadIdx.x;
  float acc = 0.f;
#pragma unroll 4
  for (int i = 0; i < 512; ++i) acc += r2t[i * 64 + g] * W[o * 512 + i];
  out[g * 10 + o] = fmaxf(acc + b[o], 0.f);
}

// ---------------- launch ----------------

extern "C" void kernel_launch(void* const* d_in, const int* in_sizes, int n_in,
                              void* d_out, int out_size, void* d_ws, size_t ws_size,
                              hipStream_t stream) {
  const float* x    = (const float*)d_in[0];
  const int*   ei   = (const int*)d_in[1];
  const float* w1_1 = (const float*)d_in[3];  const float* b1_1 = (const float*)d_in[4];
  const float* w1_2 = (const float*)d_in[5];  const float* b1_2 = (const float*)d_in[6];
  const float* w1_3 = (const float*)d_in[7];  const float* b1_3 = (const float*)d_in[8];
  const float* w2_1 = (const float*)d_in[9];  const float* b2_1 = (const float*)d_in[10];
  const float* w2_2 = (const float*)d_in[11]; const float* b2_2 = (const float*)d_in[12];
  const float* w3_1 = (const float*)d_in[13]; const float* b3_1 = (const float*)d_in[14];
  const float* l1w  = (const float*)d_in[15]; const float* l1b  = (const float*)d_in[16];
  const float* l2w  = (const float*)d_in[17]; const float* l2b  = (const float*)d_in[18];
  const float* l3w  = (const float*)d_in[19]; const float* l3b  = (const float*)d_in[20];

  char* ws = (char*)d_ws;
  size_t off = 0;
  auto alloc = [&](size_t bytes) -> char* {
    char* p = ws + off;
    off += (bytes + 255) & ~(size_t)255;
    return p;
  };
  __half* A    = (__half*)alloc((size_t)NN * 64 * 2);
  __half* Bb   = (__half*)alloc((size_t)NN * 64 * 2);
  __half* C    = (__half*)alloc((size_t)NN * 64 * 2);
  __half* T1   = (__half*)alloc((size_t)NN * 64 * 2);
  __half* T2   = (__half*)alloc((size_t)NN * 64 * 2);
  int*   deg  = (int*)alloc(NN * 4);
  float* dis  = (float*)alloc(NN * 4);
  int*   rowp = (int*)alloc((NN + 1) * 4);
  int*   fillp= (int*)alloc(NN * 4);
  unsigned* edata = (unsigned*)alloc((size_t)ET * 4);
  float* t1s  = (float*)alloc(NN * 4);
  float* g2s  = (float*)alloc(NN * 4);
  float* r1t  = (float*)alloc(512 * 64 * 4);
  float* r2t  = (float*)alloc(512 * 64 * 4);
  int*   bsum = (int*)alloc(256 * 4);
  int*   boff = (int*)alloc(256 * 4);
  float* r1p  = (float*)alloc((size_t)125 * 32768 * 4);
  float* wt11 = (float*)alloc(192 * 4);
  float* wt12 = (float*)alloc(12288 * 4);
  float* wt13 = (float*)alloc(12288 * 4);
  float* wt21 = (float*)alloc(12288 * 4);
  float* wt22 = (float*)alloc(12288 * 4);
  float* wt31 = (float*)alloc(12288 * 4);

  hipMemsetAsync(deg, 0, NN * 4, stream);

  k_deg<<<ET / 256, 256, 0, stream>>>(ei, deg);
  k_scan1<<<NN / 256, 256, 0, stream>>>(deg, dis, rowp, bsum);
  k_scan2<<<1, 256, 0, stream>>>(bsum, boff);
  k_scan3<<<NN / 256, 256, 0, stream>>>(rowp, boff, fillp);
  k_fill<<<ET / 256, 256, 0, stream>>>(ei, dis, fillp, edata);

  WXArgs wx{w1_2, w1_3, w2_1, w2_2, w3_1, w1_1,
            wt12, wt13, wt21, wt22, wt31, wt11};
  k_wx<<<81, 256, 0, stream>>>(wx);

  // layer 1 (1 -> 64 channels)
  k_prop_s<<<NN / 256, 256, 0, stream>>>(x, rowp, edata, t1s);
  k_prop_s<<<NN / 256, 256, 0, stream>>>(t1s, rowp, edata, g2s);
  k_layer1<<<NN / 4, 256, 0, stream>>>(x, t1s, g2s, wt11, b1_1, A);

  auto cheb = [&](const __half* in, const float* Wt, const float* bias,
                  int relu_f, const __half* res, __half* out) {
    k_prop64<<<NN / 4, 256, 0, stream>>>(in, rowp, edata, T1);
    k_prop64<<<NN / 4, 256, 0, stream>>>(T1, rowp, edata, T2);
    if (relu_f)
      k_mat64<1, 0><<<NN / 256, 256, 0, stream>>>(in, T1, T2, Wt, bias, nullptr, out);
    else
      k_mat64<0, 1><<<NN / 256, 256, 0, stream>>>(in, T1, T2, Wt, bias, res, out);
  };

  cheb(A,  wt12, b1_2, 1, nullptr, Bb);  // h = relu(cheb(h))
  cheb(Bb, wt13, b1_3, 0, A,       C);   // h = cheb(h) + tmp
  cheb(C,  wt21, b2_1, 1, nullptr, A);
  cheb(A,  wt22, b2_2, 0, C,       Bb);
  cheb(Bb, wt31, b3_1, 1, nullptr, C);   // final H in C

  k_lin1<<<1000, 256, 0, stream>>>(C, l1w, r1p);
  k_red<<<32768 / 256, 256, 0, stream>>>(r1p, l1b, r1t);
  k_lin2<<<512, 64, 0, stream>>>(r1t, l2w, l2b, r2t);
  k_lin3<<<10, 64, 0, stream>>>(r2t, l3w, l3b, (float*)d_out);
}